// Round 8
// baseline (127.194 us; speedup 1.0000x reference)
//
#include <hip/hip_runtime.h>
#include <math.h>

#define B_ 8
#define C_ 128
#define N_ 64
#define T_ 512
#define H_ 4
#define D_ 32
#define OUT_ 128
#define E_ 256
#define EP_ 320   // E + N self-loops
#define NEG_SLOPE 0.2f
#define BN_EPS 1e-5f

// ---- setup: wa[c][8] = W·att, edge lists, in-CSR (by dst) and out-CSR (by src)
__global__ void setup_kernel(const float* __restrict__ W,
                             const float* __restrict__ att_src,
                             const float* __restrict__ att_dst,
                             const int* __restrict__ edge_index,
                             float* __restrict__ wa,
                             int* __restrict__ esrc_g, int* __restrict__ edst_g,
                             int* __restrict__ iOff_g, int* __restrict__ iEid_g,
                             int* __restrict__ oOff_g, int* __restrict__ oEid_g) {
  __shared__ int icnt[N_], ibase[N_ + 1], ifill[N_];
  __shared__ int ocnt[N_], obase[N_ + 1], ofill[N_];
  __shared__ int esrc[EP_], edst[EP_];
  int tid = threadIdx.x;

  for (int idx = tid; idx < C_ * 8; idx += blockDim.x) {
    int c = idx >> 3, j = idx & 7, h = j & 3;
    const float* att = (j < 4) ? att_src : att_dst;
    float s = 0.f;
    for (int d = 0; d < D_; ++d)
      s += W[(c * H_ + h) * D_ + d] * att[h * D_ + d];
    wa[idx] = s;
  }
  if (tid < N_) { icnt[tid] = 0; ifill[tid] = 0; ocnt[tid] = 0; ofill[tid] = 0; }
  __syncthreads();
  for (int e = tid; e < EP_; e += blockDim.x) {
    int s, d;
    if (e < E_) { s = edge_index[e]; d = edge_index[E_ + e]; }
    else        { s = e - E_;        d = e - E_; }
    esrc[e] = s; edst[e] = d;
    atomicAdd(&icnt[d], 1);
    atomicAdd(&ocnt[s], 1);
  }
  __syncthreads();
  if (tid == 0) {
    int ai = 0, ao = 0;
    for (int n = 0; n < N_; ++n) {
      ibase[n] = ai; ai += icnt[n];
      obase[n] = ao; ao += ocnt[n];
    }
    ibase[N_] = ai; obase[N_] = ao;
  }
  __syncthreads();
  if (tid <= N_) { iOff_g[tid] = ibase[tid]; oOff_g[tid] = obase[tid]; }
  for (int e = tid; e < EP_; e += blockDim.x) {
    esrc_g[e] = esrc[e]; edst_g[e] = edst[e];
    int d = edst[e];
    int pi = ibase[d] + atomicAdd(&ifill[d], 1);
    iEid_g[pi] = e;
    int s = esrc[e];
    int po = obase[s] + atomicAdd(&ofill[s], 1);
    oEid_g[po] = e;
  }
}

// ---- kernel A: a[b][n][j][t] = sum_c x[b][c][n][t] * wa[c][j] ------------------
// grid = B*N*2 = 1024 (4 blocks/CU, 16 waves/CU), coalesced float4, 8-deep
__global__ __launch_bounds__(256, 4)
void proj_kernel(const float* __restrict__ x,
                 const float* __restrict__ wa_g,
                 float* __restrict__ a_ws) {
  __shared__ float wal[C_ * 8];
  __shared__ float4 red4[4 * 8 * 64];   // [cg][j][tq]  32 KB
  const int tid = threadIdx.x;
  const int bid = blockIdx.x;
  const int half = bid & 1;
  const int n = (bid >> 1) & 63;
  const int b = bid >> 7;

  for (int i = tid; i < C_ * 8; i += 256) wal[i] = wa_g[i];
  __syncthreads();

  const int cg = tid >> 6, tq = tid & 63;
  const float* xp = x + ((size_t)(b * C_) * N_ + n) * T_ + half * 256 + tq * 4;
  float4 acc[8];
#pragma unroll
  for (int j = 0; j < 8; ++j) { acc[j].x = 0.f; acc[j].y = 0.f; acc[j].z = 0.f; acc[j].w = 0.f; }
#pragma unroll 8
  for (int k = 0; k < 32; ++k) {
    int c = cg + 4 * k;
    float4 xv = *reinterpret_cast<const float4*>(xp + (size_t)c * (N_ * T_));
#pragma unroll
    for (int j = 0; j < 8; ++j) {
      float wj = wal[c * 8 + j];
      acc[j].x = fmaf(xv.x, wj, acc[j].x);
      acc[j].y = fmaf(xv.y, wj, acc[j].y);
      acc[j].z = fmaf(xv.z, wj, acc[j].z);
      acc[j].w = fmaf(xv.w, wj, acc[j].w);
    }
  }
#pragma unroll
  for (int j = 0; j < 8; ++j) red4[(cg * 8 + j) * 64 + tq] = acc[j];
  __syncthreads();

#pragma unroll
  for (int rep = 0; rep < 2; ++rep) {
    int ss = tid + rep * 256;
    int j = ss >> 6, tq2 = ss & 63;
    float4 v0 = red4[(0 * 8 + j) * 64 + tq2];
    float4 v1 = red4[(1 * 8 + j) * 64 + tq2];
    float4 v2 = red4[(2 * 8 + j) * 64 + tq2];
    float4 v3 = red4[(3 * 8 + j) * 64 + tq2];
    float4 r;
    r.x = (v0.x + v1.x) + (v2.x + v3.x);
    r.y = (v0.y + v1.y) + (v2.y + v3.y);
    r.z = (v0.z + v1.z) + (v2.z + v3.z);
    r.w = (v0.w + v1.w) + (v2.w + v3.w);
    *reinterpret_cast<float4*>(
        a_ws + ((size_t)(b * N_ + n) * 8 + j) * T_ + half * 256 + tq2 * 4) = r;
  }
}

// ---- kernel B1: segment softmax -> w[b][n][h][t], atomic-free ------------------
__global__ __launch_bounds__(256, 1)
void weights_kernel(const float* __restrict__ a_ws,
                    const int* __restrict__ esrc_g, const int* __restrict__ edst_g,
                    const int* __restrict__ iOff_g, const int* __restrict__ iEid_g,
                    const int* __restrict__ oOff_g, const int* __restrict__ oEid_g,
                    float* __restrict__ w_ws) {
  __shared__ float a_l[8][64][16];    // [j][n][t]  32 KB
  __shared__ float4 sc[EP_][16];      // scores -> alpha, 80 KB
  __shared__ float w_l[N_ * 64];      // [n][h][16]  16 KB
  __shared__ int eS[EP_], eD[EP_];
  __shared__ int iOff[N_ + 1], iEid[EP_], oOff[N_ + 1], oEid[EP_];
  int tid = threadIdx.x;
  int b  = blockIdx.x >> 5;
  int t0 = (blockIdx.x & 31) * 16;

  for (int i = tid; i < EP_; i += 256) {
    eS[i] = esrc_g[i]; eD[i] = edst_g[i];
    iEid[i] = iEid_g[i]; oEid[i] = oEid_g[i];
  }
  if (tid <= N_) { iOff[tid] = iOff_g[tid]; oOff[tid] = oOff_g[tid]; }
  for (int r = tid; r < 512; r += 256) {
    int n = r >> 3, j = r & 7;
    const float4* src = reinterpret_cast<const float4*>(
        a_ws + (((size_t)b * N_ + n) * 8 + j) * T_ + t0);
    float4* dst = reinterpret_cast<float4*>(&a_l[j][n][0]);
    dst[0] = src[0]; dst[1] = src[1]; dst[2] = src[2]; dst[3] = src[3];
  }
  __syncthreads();

  for (int idx = tid; idx < EP_ * 16; idx += 256) {
    int e = idx >> 4, t = idx & 15;
    int s = eS[e], d = eD[e];
    float4 v;
    v.x = a_l[0][s][t] + a_l[4][d][t];
    v.y = a_l[1][s][t] + a_l[5][d][t];
    v.z = a_l[2][s][t] + a_l[6][d][t];
    v.w = a_l[3][s][t] + a_l[7][d][t];
    v.x = v.x > 0.f ? v.x : NEG_SLOPE * v.x;
    v.y = v.y > 0.f ? v.y : NEG_SLOPE * v.y;
    v.z = v.z > 0.f ? v.z : NEG_SLOPE * v.z;
    v.w = v.w > 0.f ? v.w : NEG_SLOPE * v.w;
    sc[e][t] = v;
  }
  __syncthreads();

  for (int idx = tid; idx < N_ * 16; idx += 256) {
    int nd = idx >> 4, t = idx & 15;
    int e0 = iOff[nd], e1 = iOff[nd + 1];
    float m0 = -1e30f, m1 = -1e30f, m2 = -1e30f, m3 = -1e30f;
    for (int e = e0; e < e1; ++e) {
      float4 v = sc[iEid[e]][t];
      m0 = fmaxf(m0, v.x); m1 = fmaxf(m1, v.y);
      m2 = fmaxf(m2, v.z); m3 = fmaxf(m3, v.w);
    }
    float d0 = 0.f, d1 = 0.f, d2 = 0.f, d3 = 0.f;
    for (int e = e0; e < e1; ++e) {
      float4 v = sc[iEid[e]][t];
      d0 += __expf(v.x - m0); d1 += __expf(v.y - m1);
      d2 += __expf(v.z - m2); d3 += __expf(v.w - m3);
    }
    float i0 = 1.f / (d0 * (float)N_);
    float i1 = 1.f / (d1 * (float)N_);
    float i2 = 1.f / (d2 * (float)N_);
    float i3 = 1.f / (d3 * (float)N_);
    for (int e = e0; e < e1; ++e) {
      int ee = iEid[e];
      float4 v = sc[ee][t];
      v.x = __expf(v.x - m0) * i0; v.y = __expf(v.y - m1) * i1;
      v.z = __expf(v.z - m2) * i2; v.w = __expf(v.w - m3) * i3;
      sc[ee][t] = v;
    }
  }
  __syncthreads();

  for (int idx = tid; idx < N_ * 16; idx += 256) {
    int s = idx >> 4, t = idx & 15;
    int e0 = oOff[s], e1 = oOff[s + 1];
    float4 acc = {0.f, 0.f, 0.f, 0.f};
    for (int e = e0; e < e1; ++e) {
      float4 v = sc[oEid[e]][t];
      acc.x += v.x; acc.y += v.y; acc.z += v.z; acc.w += v.w;
    }
    w_l[s * 64 +  0 + t] = acc.x;
    w_l[s * 64 + 16 + t] = acc.y;
    w_l[s * 64 + 32 + t] = acc.z;
    w_l[s * 64 + 48 + t] = acc.w;
  }
  __syncthreads();

  const float4* wl4 = reinterpret_cast<const float4*>(w_l);
  for (int i = tid; i < 1024; i += 256) {
    int base = i * 4;
    int s = base >> 6;
    int rem = base & 63;
    int h = rem >> 4;
    int tt = rem & 15;
    *reinterpret_cast<float4*>(
        w_ws + ((size_t)(b * N_ + s) * H_ + h) * T_ + t0 + tt) = wl4[i];
  }
}

// ---- kernel K3: fused agg + out. block = (b, 16-t chunk), grid 256 = 1/CU.
// Streams its 512 KB x-slice exactly once in 8-c octets (full-line coalesced),
// double-buffered LDS with XOR-quad swizzle; y accumulated per (c,t); then
// y·W + bias + BN epilogue in-block. Zero redundant global reads.
#define CS_STRIDE 1028   // floats per c-plane in x tile (1028 % 32 == 4, 16B-aligned)
__global__ __launch_bounds__(256, 1)
void aggout_kernel(const float* __restrict__ x,
                   const float* __restrict__ w_ws,
                   const float* __restrict__ W,
                   const float* __restrict__ bias,
                   const float* __restrict__ bn_gamma,
                   const float* __restrict__ bn_beta,
                   const float* __restrict__ bn_mean,
                   const float* __restrict__ bn_var,
                   float* __restrict__ out) {
  __shared__ float xa[2][8 * CS_STRIDE];   // 2 x 32.9 KB
  __shared__ float y_l[4 * 128 * 17];      // 34.8 KB  [h][c][t+pad]
  __shared__ float w_l[N_ * 16 * 4];       // 16 KB    [n][t][h]
  __shared__ float scr[8 * 16 * 4];        // 2 KB partial-reduce scratch

  const int tid = threadIdx.x;
  const int b  = blockIdx.x & 7;
  const int tc = blockIdx.x >> 3;          // 0..31
  const int t0 = tc * 16;

  // stage decode: 4 lanes per 64-B row -> 16 full lines per wave-instr
  const int sq = tid & 3;                  // quad within row
  const int sn = tid >> 2;                 // n (0..63); c = octet*8 + pass
  // compute decode
  const int cs = tid >> 5;                 // c-slot 0..7
  const int tt = (tid >> 1) & 15;          // local t
  const int nh = tid & 1;                  // n-half

  const size_t xrow = (size_t)N_ * T_;
  const float* xbase = x + (size_t)b * C_ * xrow + (size_t)sn * T_ + t0 + sq * 4;

  // ---- prologue: stage w tile [n][t][h] ----
  {
    int n = tid >> 2, h = tid & 3;
    const float* wp = w_ws + ((size_t)(b * N_ + n) * H_ + h) * T_ + t0;
    float4 a0 = *reinterpret_cast<const float4*>(wp);
    float4 a1 = *reinterpret_cast<const float4*>(wp + 4);
    float4 a2 = *reinterpret_cast<const float4*>(wp + 8);
    float4 a3 = *reinterpret_cast<const float4*>(wp + 12);
    float vals[16] = {a0.x,a0.y,a0.z,a0.w, a1.x,a1.y,a1.z,a1.w,
                      a2.x,a2.y,a2.z,a2.w, a3.x,a3.y,a3.z,a3.w};
#pragma unroll
    for (int t = 0; t < 16; ++t) w_l[(n * 16 + t) * 4 + h] = vals[t];
  }
  // ---- prologue: stage x octet 0 ----
  {
    float4 pre[8];
#pragma unroll
    for (int p = 0; p < 8; ++p)
      pre[p] = *reinterpret_cast<const float4*>(xbase + (size_t)p * xrow);
    float* dst = &xa[0][0];
    const int wq = (sq ^ (sn & 3)) << 2;
#pragma unroll
    for (int p = 0; p < 8; ++p)
      *reinterpret_cast<float4*>(&dst[p * CS_STRIDE + sn * 16 + wq]) = pre[p];
  }
  __syncthreads();

  // ---- main loop over 16 c-octets ----
  for (int o = 0; o < 16; ++o) {
    float4 pre[8];
    if (o < 15) {
      const float* src = xbase + (size_t)(o + 1) * 8 * xrow;
#pragma unroll
      for (int p = 0; p < 8; ++p)
        pre[p] = *reinterpret_cast<const float4*>(src + (size_t)p * xrow);
    }
    // compute: y[h] for (c = o*8+cs, t0+tt), n in [nh*32, nh*32+32)
    const float* xb = &xa[o & 1][cs * CS_STRIDE];
    float y0 = 0.f, y1 = 0.f, y2 = 0.f, y3 = 0.f;
#pragma unroll 4
    for (int i = 0; i < 32; ++i) {
      int n = nh * 32 + i;
      float xv = xb[n * 16 + (tt ^ ((n & 3) << 2))];
      float4 wv = *reinterpret_cast<const float4*>(&w_l[(n * 16 + tt) * 4]);
      y0 = fmaf(xv, wv.x, y0);
      y1 = fmaf(xv, wv.y, y1);
      y2 = fmaf(xv, wv.z, y2);
      y3 = fmaf(xv, wv.w, y3);
    }
    if (nh) {
      float4 v; v.x = y0; v.y = y1; v.z = y2; v.w = y3;
      *reinterpret_cast<float4*>(&scr[(cs * 16 + tt) * 4]) = v;
    }
    __syncthreads();
    if (!nh) {
      float4 v = *reinterpret_cast<const float4*>(&scr[(cs * 16 + tt) * 4]);
      int c = o * 8 + cs;
      y_l[0 * 2176 + c * 17 + tt] = y0 + v.x;
      y_l[1 * 2176 + c * 17 + tt] = y1 + v.y;
      y_l[2 * 2176 + c * 17 + tt] = y2 + v.z;
      y_l[3 * 2176 + c * 17 + tt] = y3 + v.w;
    }
    if (o < 15) {
      float* dst = &xa[(o + 1) & 1][0];
      const int wq = (sq ^ (sn & 3)) << 2;
#pragma unroll
      for (int p = 0; p < 8; ++p)
        *reinterpret_cast<float4*>(&dst[p * CS_STRIDE + sn * 16 + wq]) = pre[p];
    }
    __syncthreads();
  }

  // ---- epilogue: out[oc][t] = BN(sum_c y[h][c][t]*W[c][h][d] + bias) ----
  {
    const int t3 = tid & 15, g3 = tid >> 4;  // 16 groups
    const int h = g3 >> 2, d0 = (g3 & 3) * 8;
    float acc[8];
#pragma unroll
    for (int k = 0; k < 8; ++k) acc[k] = 0.f;
#pragma unroll 4
    for (int c = 0; c < C_; ++c) {
      float yv = y_l[h * 2176 + c * 17 + t3];
      const float4 wv0 = *reinterpret_cast<const float4*>(
          &W[((size_t)c * H_ + h) * D_ + d0]);
      const float4 wv1 = *reinterpret_cast<const float4*>(
          &W[((size_t)c * H_ + h) * D_ + d0 + 4]);
      acc[0] = fmaf(yv, wv0.x, acc[0]); acc[1] = fmaf(yv, wv0.y, acc[1]);
      acc[2] = fmaf(yv, wv0.z, acc[2]); acc[3] = fmaf(yv, wv0.w, acc[3]);
      acc[4] = fmaf(yv, wv1.x, acc[4]); acc[5] = fmaf(yv, wv1.y, acc[5]);
      acc[6] = fmaf(yv, wv1.z, acc[6]); acc[7] = fmaf(yv, wv1.w, acc[7]);
    }
#pragma unroll
    for (int k = 0; k < 8; ++k) {
      int oc = h * D_ + d0 + k;
      float scale = bn_gamma[oc] * rsqrtf(bn_var[oc] + BN_EPS);
      float shift = bn_beta[oc] - bn_mean[oc] * scale;
      out[((size_t)b * OUT_ + oc) * T_ + t0 + t3] =
          (acc[k] + bias[oc]) * scale + shift;
    }
  }
}

extern "C" void kernel_launch(void* const* d_in, const int* in_sizes, int n_in,
                              void* d_out, int out_size, void* d_ws, size_t ws_size,
                              hipStream_t stream) {
  const float* x        = (const float*)d_in[0];
  const float* W        = (const float*)d_in[1];
  const float* att_src  = (const float*)d_in[2];
  const float* att_dst  = (const float*)d_in[3];
  const float* bias     = (const float*)d_in[4];
  const float* bn_gamma = (const float*)d_in[5];
  const float* bn_beta  = (const float*)d_in[6];
  const float* bn_mean  = (const float*)d_in[7];
  const float* bn_var   = (const float*)d_in[8];
  const int* edge_index = (const int*)d_in[9];
  float* out = (float*)d_out;

  char* ws = (char*)d_ws;
  float* wa    = (float*)ws;
  int* esrc_g  = (int*)(ws + 4096);
  int* edst_g  = (int*)(ws + 6144);
  int* iOff_g  = (int*)(ws + 8192);
  int* iEid_g  = (int*)(ws + 8704);
  int* oOff_g  = (int*)(ws + 10752);
  int* oEid_g  = (int*)(ws + 11264);
  float* a_ws  = (float*)(ws + 16384);        // 8 MB  [b][n][j][t]
  float* w_ws  = (float*)(ws + 16384 + (size_t)8 * 1024 * 1024);  // 4 MB [b][n][h][t]

  setup_kernel<<<1, 256, 0, stream>>>(W, att_src, att_dst, edge_index, wa,
                                      esrc_g, edst_g, iOff_g, iEid_g, oOff_g, oEid_g);
  proj_kernel<<<B_ * N_ * 2, 256, 0, stream>>>(x, wa, a_ws);
  weights_kernel<<<B_ * (T_ / 16), 256, 0, stream>>>(a_ws, esrc_g, edst_g,
                                                     iOff_g, iEid_g, oOff_g, oEid_g,
                                                     w_ws);
  aggout_kernel<<<256, 256, 0, stream>>>(x, w_ws, W, bias, bn_gamma, bn_beta,
                                         bn_mean, bn_var, out);
}